// Round 11
// baseline (52.435 us; speedup 1.0000x reference)
//
#include <hip/hip_runtime.h>
#include <hip/hip_bf16.h>

// Problem constants (reference: N,E,H,L = 64,64,768,512; eps=1e-12)
#define Nn 64
#define Ee 64
#define Hh 768
#define Ll 512
#define NEH (Nn * Ee * Hh) // 3145728 state elems
#define NEL (Nn * Ee * Ll) // 2097152 mapping elems

typedef __attribute__((ext_vector_type(8))) short bf16x8; // 8 bf16 = 4 VGPRs (MFMA A/B frag)
typedef __attribute__((ext_vector_type(4))) float f32x4;  // MFMA C/D frag

// ---------------------------------------------------------------------------
// Pre-pass: fp32 -> bf16 convert + transpose, LDS-tiled, both sides coalesced.
//   sT[n][h][e]  (H x E per n)   mT[n][l][e]  (L x E per n)
// (R3 form; <5.7us/pass by R8 rank evidence.)
// ---------------------------------------------------------------------------
__global__ __launch_bounds__(256) void cvt_transpose(
    const float* __restrict__ state, const float* __restrict__ mapping,
    __hip_bfloat16* __restrict__ sT, __hip_bfloat16* __restrict__ mT)
{
    __shared__ unsigned short lds[64][66]; // [x][e]

    int b = blockIdx.x;
    const float* src;
    __hip_bfloat16* dst;
    int W, x0;
    if (b < Nn * (Hh / 64)) {            // state tiles
        int n = b / (Hh / 64);
        x0 = (b % (Hh / 64)) * 64;
        src = state + (size_t)n * Ee * Hh;
        dst = sT + (size_t)n * Hh * Ee;
        W = Hh;
    } else {                              // mapping tiles
        b -= Nn * (Hh / 64);
        int n = b / (Ll / 64);
        x0 = (b % (Ll / 64)) * 64;
        src = mapping + (size_t)n * Ee * Ll;
        dst = mT + (size_t)n * Ll * Ee;
        W = Ll;
    }

    // Read phase: each thread loads float2 (2 x's) of one e-row.
    const int xr = (threadIdx.x & 31) * 2;
    const int er = threadIdx.x >> 5;  // 0..7
#pragma unroll
    for (int i = 0; i < 8; ++i) {
        int e = i * 8 + er;
        float2 v = *reinterpret_cast<const float2*>(src + (size_t)e * W + x0 + xr);
        union { __hip_bfloat16 b16; unsigned short u; } c0, c1;
        c0.b16 = __float2bfloat16(v.x);
        c1.b16 = __float2bfloat16(v.y);
        lds[xr][e]     = c0.u;
        lds[xr + 1][e] = c1.u;
    }
    __syncthreads();

    // Write phase: each thread packs 4 bf16 (contiguous e) -> one 8B store.
    const int e4 = (threadIdx.x & 15) * 4;
    const int xw = threadIdx.x >> 4;   // 0..15
    unsigned short* dsts = reinterpret_cast<unsigned short*>(dst);
#pragma unroll
    for (int i = 0; i < 4; ++i) {
        int x = i * 16 + xw;
        uint2 v;
        v.x = *reinterpret_cast<const unsigned int*>(&lds[x][e4]);
        v.y = *reinterpret_cast<const unsigned int*>(&lds[x][e4 + 2]);
        *reinterpret_cast<uint2*>(dsts + (size_t)(x0 + x) * Ee + e4) = v;
    }
}

// ---------------------------------------------------------------------------
// STATS PASS: exact R3 gemm_ln arithmetic (same frags, same MFMA order ->
// bit-identical acc -> bit-identical mu/rstd), but instead of storing the
// 98 MB output it writes only (mu, rstd) per l-row (256 KB total).
// Pure-compute kernel: no store phase to phase-lock on.
// ---------------------------------------------------------------------------
__global__ __launch_bounds__(256) void stats_pass(
    const __hip_bfloat16* __restrict__ sT, // [N][H][E]
    const __hip_bfloat16* __restrict__ mT, // [N][L][E]
    float2* __restrict__ stats)            // [N*L] = (mu, rstd)
{
    __shared__ float redS[32][4];
    __shared__ float redQ[32][4];

    const int p    = blockIdx.x;
    const int n    = ((p >> 7) << 3) | (p & 7);
    const int l0   = ((p >> 3) & 15) << 5; // 32 rows per tile
    const int tid  = threadIdx.x;
    const int w    = tid >> 6;
    const int lane = tid & 63;
    const int g    = lane >> 4;
    const int c    = lane & 15;

    bf16x8 b0[2], b1[2];
#pragma unroll
    for (int u = 0; u < 2; ++u) {
        const __hip_bfloat16* Brow = mT + (size_t)(n * Ll + l0 + u * 16 + c) * Ee + g * 8;
        b0[u] = *reinterpret_cast<const bf16x8*>(Brow);
        b1[u] = *reinterpret_cast<const bf16x8*>(Brow + 32);
    }

    f32x4 acc[12][2];
#pragma unroll
    for (int t = 0; t < 12; ++t)
#pragma unroll
        for (int u = 0; u < 2; ++u) acc[t][u] = (f32x4){0.f, 0.f, 0.f, 0.f};

    const __hip_bfloat16* Abase = sT + (size_t)(n * Hh + w * 192 + c) * Ee + g * 8;
#pragma unroll
    for (int t = 0; t < 12; ++t) {
        const __hip_bfloat16* ap = Abase + (size_t)t * 16 * Ee;
        bf16x8 a0 = *reinterpret_cast<const bf16x8*>(ap);
        bf16x8 a1 = *reinterpret_cast<const bf16x8*>(ap + 32);
#pragma unroll
        for (int u = 0; u < 2; ++u) {
            acc[t][u] = __builtin_amdgcn_mfma_f32_16x16x32_bf16(a0, b0[u], acc[t][u], 0, 0, 0);
            acc[t][u] = __builtin_amdgcn_mfma_f32_16x16x32_bf16(a1, b1[u], acc[t][u], 0, 0, 0);
        }
    }

    float s[2] = {0.f, 0.f}, q[2] = {0.f, 0.f};
#pragma unroll
    for (int t = 0; t < 12; ++t)
#pragma unroll
        for (int u = 0; u < 2; ++u)
#pragma unroll
            for (int r = 0; r < 4; ++r) {
                float v = acc[t][u][r];
                s[u] += v;
                q[u] += v * v;
            }
#pragma unroll
    for (int off = 16; off < 64; off <<= 1)
#pragma unroll
        for (int u = 0; u < 2; ++u) {
            s[u] += __shfl_xor(s[u], off, 64);
            q[u] += __shfl_xor(q[u], off, 64);
        }
    if (g == 0) {
#pragma unroll
        for (int u = 0; u < 2; ++u) {
            redS[u * 16 + c][w] = s[u];
            redQ[u * 16 + c][w] = q[u];
        }
    }
    __syncthreads();

    // Only the 16 threads (w==0, g==0) compute+store; values identical across waves.
    if (tid < 16) {
#pragma unroll
        for (int u = 0; u < 2; ++u) {
            int li = u * 16 + c;
            float S = redS[li][0] + redS[li][1] + redS[li][2] + redS[li][3];
            float Q = redQ[li][0] + redQ[li][1] + redQ[li][2] + redQ[li][3];
            float m = S * (1.f / Hh);
            float v = Q * (1.f / Hh) - m * m;
            stats[n * Ll + l0 + li] = make_float2(m, rsqrtf(v + 1e-12f));
        }
    }
}

// ---------------------------------------------------------------------------
// MAIN PASS: same GEMM fragments, but mu/rstd are PRE-COMPUTED, so each
// 16x16 tile is normalized and stored IMMEDIATELY after its 2 MFMAs.
// No LDS, no barriers, no shuffles; acc is 2 frags (not 24) -> ~70 VGPR ->
// ~6-7 waves/SIMD; stores spread uniformly through the t-loop (unroll 1)
// => continuous chip-wide write stream instead of phase-locked bursts.
// ---------------------------------------------------------------------------
__global__ __launch_bounds__(256) void gemm_store(
    const __hip_bfloat16* __restrict__ sT, // [N][H][E]
    const __hip_bfloat16* __restrict__ mT, // [N][L][E]
    const float2* __restrict__ stats,      // [N*L] = (mu, rstd)
    const float* __restrict__ gamma,
    const float* __restrict__ beta,
    float* __restrict__ out)               // [N][L][H]
{
    const int p    = blockIdx.x;
    const int n    = ((p >> 7) << 3) | (p & 7);
    const int l0   = ((p >> 3) & 15) << 5; // 32 rows per tile
    const int tid  = threadIdx.x;
    const int w    = tid >> 6;
    const int lane = tid & 63;
    const int g    = lane >> 4;
    const int c    = lane & 15;

    bf16x8 b0[2], b1[2];
    float2 st[2];
    float* orow[2];
#pragma unroll
    for (int u = 0; u < 2; ++u) {
        const int l = l0 + u * 16 + c;
        const __hip_bfloat16* Brow = mT + (size_t)(n * Ll + l) * Ee + g * 8;
        b0[u] = *reinterpret_cast<const bf16x8*>(Brow);
        b1[u] = *reinterpret_cast<const bf16x8*>(Brow + 32);
        st[u] = stats[n * Ll + l];
        orow[u] = out + (size_t)(n * Ll + l) * Hh;
    }

    const __hip_bfloat16* Abase = sT + (size_t)(n * Hh + w * 192 + c) * Ee + g * 8;
#pragma unroll 1
    for (int t = 0; t < 12; ++t) {
        const __hip_bfloat16* ap = Abase + (size_t)t * 16 * Ee;
        bf16x8 a0 = *reinterpret_cast<const bf16x8*>(ap);
        bf16x8 a1 = *reinterpret_cast<const bf16x8*>(ap + 32);

        const int hb = w * 192 + t * 16 + g * 4;
        f32x4 gm = *reinterpret_cast<const f32x4*>(gamma + hb);
        f32x4 bt = *reinterpret_cast<const f32x4*>(beta + hb);

#pragma unroll
        for (int u = 0; u < 2; ++u) {
            f32x4 acc = (f32x4){0.f, 0.f, 0.f, 0.f};
            acc = __builtin_amdgcn_mfma_f32_16x16x32_bf16(a0, b0[u], acc, 0, 0, 0);
            acc = __builtin_amdgcn_mfma_f32_16x16x32_bf16(a1, b1[u], acc, 0, 0, 0);
            f32x4 v;
#pragma unroll
            for (int r = 0; r < 4; ++r)
                v[r] = (acc[r] - st[u].x) * st[u].y * gm[r] + bt[r];
            *reinterpret_cast<f32x4*>(orow[u] + hb) = v;
        }
    }
}

extern "C" void kernel_launch(void* const* d_in, const int* in_sizes, int n_in,
                              void* d_out, int out_size, void* d_ws, size_t ws_size,
                              hipStream_t stream)
{
    const float* state   = (const float*)d_in[0]; // (N,E,H)
    const float* mapping = (const float*)d_in[1]; // (N,E,L)
    const float* gamma   = (const float*)d_in[2]; // (H,)
    const float* beta    = (const float*)d_in[3]; // (H,)
    float* out           = (float*)d_out;         // (N,L,H)

    __hip_bfloat16* sT = (__hip_bfloat16*)d_ws;       // N*H*E bf16
    __hip_bfloat16* mT = sT + NEH;                    // N*L*E bf16
    float2* stats      = (float2*)(mT + NEL);         // N*L float2 (256 KB); ws >= 11 MB

    const int tiles = Nn * (Hh / 64) + Nn * (Ll / 64); // 768 + 512 = 1280
    cvt_transpose<<<tiles, 256, 0, stream>>>(state, mapping, sT, mT);
    stats_pass<<<Nn * (Ll / 32), 256, 0, stream>>>(sT, mT, stats);
    gemm_store<<<Nn * (Ll / 32), 256, 0, stream>>>(sT, mT, stats, gamma, beta, out);
}

// Round 12
// 45.859 us; speedup vs baseline: 1.1434x; 1.1434x over previous
//
#include <hip/hip_runtime.h>
#include <hip/hip_bf16.h>

// Problem constants (reference: N,E,H,L = 64,64,768,512; eps=1e-12)
#define Nn 64
#define Ee 64
#define Hh 768
#define Ll 512
#define NEH (Nn * Ee * Hh) // 3145728 state elems
#define NEL (Nn * Ee * Ll) // 2097152 mapping elems

typedef __attribute__((ext_vector_type(8))) short bf16x8; // 8 bf16 = 4 VGPRs (MFMA A/B frag)
typedef __attribute__((ext_vector_type(4))) float f32x4;  // MFMA C/D frag

// ---------------------------------------------------------------------------
// Pre-pass: fp32 -> bf16 convert + transpose, LDS-tiled, both sides coalesced.
//   sT[n][h][e]  (H x E per n)   mT[n][l][e]  (L x E per n)
// (R3 form; <5.7us/pass by R8 rank evidence.)
// ---------------------------------------------------------------------------
__global__ __launch_bounds__(256) void cvt_transpose(
    const float* __restrict__ state, const float* __restrict__ mapping,
    __hip_bfloat16* __restrict__ sT, __hip_bfloat16* __restrict__ mT)
{
    __shared__ unsigned short lds[64][66]; // [x][e]

    int b = blockIdx.x;
    const float* src;
    __hip_bfloat16* dst;
    int W, x0;
    if (b < Nn * (Hh / 64)) {            // state tiles
        int n = b / (Hh / 64);
        x0 = (b % (Hh / 64)) * 64;
        src = state + (size_t)n * Ee * Hh;
        dst = sT + (size_t)n * Hh * Ee;
        W = Hh;
    } else {                              // mapping tiles
        b -= Nn * (Hh / 64);
        int n = b / (Ll / 64);
        x0 = (b % (Ll / 64)) * 64;
        src = mapping + (size_t)n * Ee * Ll;
        dst = mT + (size_t)n * Ll * Ee;
        W = Ll;
    }

    // Read phase: each thread loads float2 (2 x's) of one e-row.
    const int xr = (threadIdx.x & 31) * 2;
    const int er = threadIdx.x >> 5;  // 0..7
#pragma unroll
    for (int i = 0; i < 8; ++i) {
        int e = i * 8 + er;
        float2 v = *reinterpret_cast<const float2*>(src + (size_t)e * W + x0 + xr);
        union { __hip_bfloat16 b16; unsigned short u; } c0, c1;
        c0.b16 = __float2bfloat16(v.x);
        c1.b16 = __float2bfloat16(v.y);
        lds[xr][e]     = c0.u;
        lds[xr + 1][e] = c1.u;
    }
    __syncthreads();

    // Write phase: each thread packs 4 bf16 (contiguous e) -> one 8B store.
    const int e4 = (threadIdx.x & 15) * 4;
    const int xw = threadIdx.x >> 4;   // 0..15
    unsigned short* dsts = reinterpret_cast<unsigned short*>(dst);
#pragma unroll
    for (int i = 0; i < 4; ++i) {
        int x = i * 16 + xw;
        uint2 v;
        v.x = *reinterpret_cast<const unsigned int*>(&lds[x][e4]);
        v.y = *reinterpret_cast<const unsigned int*>(&lds[x][e4 + 2]);
        *reinterpret_cast<uint2*>(dsts + (size_t)(x0 + x) * Ee + e4) = v;
    }
}

// ---------------------------------------------------------------------------
// Fused GEMM (out[n,l,h] = sum_e mapping[n,e,l]*state[n,e,h]) + LayerNorm(H).
// A = state frag (rows = h), B = mapping frag (cols = l); lane's f32x4 acc is
// 4 consecutive h -> direct float4 stores. Same verified fragment math.
//
// R12 (from R11's accounting + R8's Occupancy=10.7%): the kernel was
// LATENCY-SERIALIZED at 1 resident block/CU (248 unified regs), pipes <12%
// busy. Fix = 16 waves/CU at unchanged read traffic:
//   - 1024-thread blocks; wave w owns h slice [w*48, w*48+48) (3 t-tiles,
//     acc[3][2] = 24 accum regs; ~100 total, forced <=128 by launch shape).
//   - Block covers 32l x 768h of one n => same sT/mT bytes as R3.
//   - Grid 256, persistent: one block per CU, 4 l-tiles each, no tail;
//     tile i's stores drain under tile i+1's loads/MFMA (no endpgm between).
//   - LN cross-wave reduce: 16 partials via parity-buffered LDS (barrier-
//     safe two tiles apart; one barrier per tile).
// ---------------------------------------------------------------------------
__global__ __launch_bounds__(1024) void gemm_ln(
    const __hip_bfloat16* __restrict__ sT, // [N][H][E]
    const __hip_bfloat16* __restrict__ mT, // [N][L][E]
    const float* __restrict__ gamma,
    const float* __restrict__ beta,
    float* __restrict__ out)               // [N][L][H]
{
    __shared__ float redS[2][32][16];
    __shared__ float redQ[2][32][16];

    const int b    = blockIdx.x;                 // 0..255, one per CU
    const int n    = ((b >> 5) << 3) | (b & 7);  // 4 blocks per n, same XCD slot
    const int sgrp = (b >> 3) & 3;               // which 4 of the 16 l-tiles
    const int tid  = threadIdx.x;
    const int w    = tid >> 6;        // wave 0..15 -> h slice [w*48, w*48+48)
    const int lane = tid & 63;
    const int g    = lane >> 4;       // k-group 0..3 (also h sub-offset in D)
    const int c    = lane & 15;       // operand row index (h for A, l for B)

    const __hip_bfloat16* Abase = sT + (size_t)(n * Hh + w * 48 + c) * Ee + g * 8;

#pragma unroll 1
    for (int it = 0; it < 4; ++it) {
        const int l0 = (sgrp * 4 + it) * 32;     // 32 l-rows per tile
        const int pb = it & 1;                   // parity buffer

        // B fragments (mapping rows l0+u*16+c), k = 8*g + j and +32
        bf16x8 b0[2], b1[2];
#pragma unroll
        for (int u = 0; u < 2; ++u) {
            const __hip_bfloat16* Brow = mT + (size_t)(n * Ll + l0 + u * 16 + c) * Ee + g * 8;
            b0[u] = *reinterpret_cast<const bf16x8*>(Brow);
            b1[u] = *reinterpret_cast<const bf16x8*>(Brow + 32);
        }

        f32x4 acc[3][2];
#pragma unroll
        for (int t = 0; t < 3; ++t)
#pragma unroll
            for (int u = 0; u < 2; ++u) acc[t][u] = (f32x4){0.f, 0.f, 0.f, 0.f};

#pragma unroll
        for (int t = 0; t < 3; ++t) {
            const __hip_bfloat16* ap = Abase + (size_t)t * 16 * Ee;
            bf16x8 a0 = *reinterpret_cast<const bf16x8*>(ap);
            bf16x8 a1 = *reinterpret_cast<const bf16x8*>(ap + 32);
#pragma unroll
            for (int u = 0; u < 2; ++u) {
                acc[t][u] = __builtin_amdgcn_mfma_f32_16x16x32_bf16(a0, b0[u], acc[t][u], 0, 0, 0);
                acc[t][u] = __builtin_amdgcn_mfma_f32_16x16x32_bf16(a1, b1[u], acc[t][u], 0, 0, 0);
            }
        }

        // ---------------- LayerNorm partials (48 h per wave) ----------------
        float s[2] = {0.f, 0.f}, q[2] = {0.f, 0.f};
#pragma unroll
        for (int t = 0; t < 3; ++t)
#pragma unroll
            for (int u = 0; u < 2; ++u)
#pragma unroll
                for (int r = 0; r < 4; ++r) {
                    float v = acc[t][u][r];
                    s[u] += v;
                    q[u] += v * v;
                }
        // Sum over g (lanes c, c+16, c+32, c+48): two butterfly steps.
#pragma unroll
        for (int off = 16; off < 64; off <<= 1)
#pragma unroll
            for (int u = 0; u < 2; ++u) {
                s[u] += __shfl_xor(s[u], off, 64);
                q[u] += __shfl_xor(q[u], off, 64);
            }
        if (g == 0) {
#pragma unroll
            for (int u = 0; u < 2; ++u) {
                redS[pb][u * 16 + c][w] = s[u];
                redQ[pb][u * 16 + c][w] = q[u];
            }
        }
        __syncthreads();
        // (parity safety: next write to this buffer is 2 tiles away; the
        //  intervening tile's barrier orders all reads before that write)

        float mu[2], rstd[2];
#pragma unroll
        for (int u = 0; u < 2; ++u) {
            int li = u * 16 + c;
            float S = 0.f, Q = 0.f;
#pragma unroll
            for (int ww = 0; ww < 16; ++ww) {
                S += redS[pb][li][ww];
                Q += redQ[pb][li][ww];
            }
            float m = S * (1.f / Hh);
            float v = Q * (1.f / Hh) - m * m;
            mu[u]   = m;
            rstd[u] = rsqrtf(v + 1e-12f);
        }

        // -------- Epilogue: normalize + gamma/beta + float4 stores --------
        // Stores drain during the NEXT tile's load/MFMA phase.
#pragma unroll
        for (int t = 0; t < 3; ++t) {
            int hb = w * 48 + t * 16 + g * 4;
            f32x4 gm = *reinterpret_cast<const f32x4*>(gamma + hb);
            f32x4 bt = *reinterpret_cast<const f32x4*>(beta + hb);
#pragma unroll
            for (int u = 0; u < 2; ++u) {
                f32x4 v;
#pragma unroll
                for (int r = 0; r < 4; ++r)
                    v[r] = (acc[t][u][r] - mu[u]) * rstd[u] * gm[r] + bt[r];
                *reinterpret_cast<f32x4*>(
                    out + (size_t)(n * Ll + l0 + u * 16 + c) * Hh + hb) = v;
            }
        }
    }
}

extern "C" void kernel_launch(void* const* d_in, const int* in_sizes, int n_in,
                              void* d_out, int out_size, void* d_ws, size_t ws_size,
                              hipStream_t stream)
{
    const float* state   = (const float*)d_in[0]; // (N,E,H)
    const float* mapping = (const float*)d_in[1]; // (N,E,L)
    const float* gamma   = (const float*)d_in[2]; // (H,)
    const float* beta    = (const float*)d_in[3]; // (H,)
    float* out           = (float*)d_out;         // (N,L,H)

    __hip_bfloat16* sT = (__hip_bfloat16*)d_ws;   // N*H*E bf16
    __hip_bfloat16* mT = sT + NEH;                // N*L*E bf16  (total ws use: 10.5 MB)

    const int tiles = Nn * (Hh / 64) + Nn * (Ll / 64); // 768 + 512 = 1280
    cvt_transpose<<<tiles, 256, 0, stream>>>(state, mapping, sT, mT);
    gemm_ln<<<256, 1024, 0, stream>>>(sT, mT, gamma, beta, out);
}